// Round 10
// baseline (6622.253 us; speedup 1.0000x reference)
//
#include <hip/hip_runtime.h>
#include <cstddef>

#define BB 256   // batch
#define TT 4096  // time steps
#define HH 64    // hidden
#define NT 256   // threads: 64 units x 4 K-slices
#define CH 16    // chunk depth (steps)
#define NCH (TT / CH)

// smem float layout (bank-tuned):
//   [8, 2056)    xc: 2 bufs x 16 rows x 64 cols  (base ≡ 8 mod 32)
//   [2064, 3088) hist ring: 16 rows x 64         (base ≡ 16 mod 32)
#define XC0   8
#define HIST0 2064
#define SMEMF 3092

#define LOG2E  1.442695041f
#define LOG2E2 2.885390082f

// produced-chunk counters for layer outputs 0..2 (layer l+1 polls row l).
__device__ int g_flags[3 * BB];

__global__ void zero_flags_kernel() { g_flags[threadIdx.x] = 0; }

__device__ __forceinline__ float dpp_xor1(float x) {  // lane ^= 1 (quad_perm)
    return __int_as_float(__builtin_amdgcn_mov_dpp(__float_as_int(x), 0xB1, 0xF, 0xF, true));
}
__device__ __forceinline__ float dpp_xor2(float x) {  // lane ^= 2 (quad_perm)
    return __int_as_float(__builtin_amdgcn_mov_dpp(__float_as_int(x), 0x4E, 0xF, 0xF, true));
}
__device__ __forceinline__ float frcp(float x) { return __builtin_amdgcn_rcpf(x); }

// Raw workgroup barrier: LDS-ordering only (no vmcnt drain).
__device__ __forceinline__ void lds_barrier() {
    asm volatile("s_waitcnt lgkmcnt(0)\n\ts_barrier" ::: "memory");
}

// 4-layer pipelined LSTM, 256 threads/block (4 waves — R9 post-mortem: VALU
// issue-bound, overhead is per-wave, so fewer/fatter waves). Thread
// (j = tid>>2, e = tid&3): partials of unit j's 4 gate rows over K-slice e
// (e<2: h cols [32e,+32); e>=2: x cols [32(e-2),+32)); 128 weight floats per
// thread (fits (2,2) 256-reg budget). Reduce over 4 lanes = xor1 + xor2 only
// (the 8-split's xor4/ds_swizzle stage is GONE). Weights pre-scaled by log2e
// (2*log2e for tanh gate q==2); bias*ksc/4 folded into the first FMA (4-lane
// reduce sums 4 copies). Pipeline identical to verified R9: grid = 1024
// blocks (l = bid>>8, b = bid&255), 2 blocks/CU co-resident, chunk-granular
// acquire/release flags, seq in-place.
__global__ __attribute__((amdgpu_flat_work_group_size(NT, NT), amdgpu_waves_per_eu(2, 2)))
void lstm_pipe(const float* __restrict__ xg,    // x [B][T][6]
               const float* __restrict__ Wih0,  // [256][6]
               const float* __restrict__ WihR,  // [3][256][64]
               const float* __restrict__ Whh4,  // [4][256][64]
               const float* __restrict__ bih4,  // [4][256]
               const float* __restrict__ bhh4,  // [4][256]
               float* __restrict__ seq)         // [T][B][64] in-place
{
    const int bid = blockIdx.x;
    const int l   = bid >> 8;
    const int b   = bid & (BB - 1);
    const bool FIRST = (l == 0);
    const bool LAST  = (l == 3);
    const float* Wih = FIRST ? Wih0 : (WihR + (size_t)(l - 1) * 256 * HH);
    const float* Whh = Whh4 + (size_t)l * 256 * HH;
    const float* bih = bih4 + l * 256;
    const float* bhh = bhh4 + l * 256;
    int* const fin  = &g_flags[(l - 1) * BB + b];  // dereferenced only if l>0
    int* const fout = &g_flags[l * BB + b];        // dereferenced only if l<3

    const int tid = threadIdx.x;
    const int j   = tid >> 2;
    const int e   = tid & 3;
    const bool kbh = (e < 2);          // h-slice lane vs x-slice lane
    const bool qb0 = (e & 1) != 0;
    const bool qb1 = (e & 2) != 0;

    __shared__ __align__(16) float smem[SMEMF];

    // ---- weights: [gate][8] float4 = 128 floats, all-static indexing ----
    float4 w[4][8];
#pragma unroll
    for (int q = 0; q < 4; ++q)
#pragma unroll
        for (int m = 0; m < 8; ++m) w[q][m] = make_float4(0.f, 0.f, 0.f, 0.f);

    if (!FIRST || kbh) {
        const float* Wp = kbh ? Whh : Wih;
        const int col0 = (kbh ? e : (e - 2)) * 32;
#pragma unroll
        for (int q = 0; q < 4; ++q) {
            const float ksc = (q == 2) ? LOG2E2 : LOG2E;
            const float4* rp = (const float4*)(Wp + ((q << 6) + j) * HH + col0);
#pragma unroll
            for (int m = 0; m < 8; ++m) {
                float4 v = rp[m];
                w[q][m] = make_float4(v.x * ksc, v.y * ksc, v.z * ksc, v.w * ksc);
            }
        }
    } else if (e == 2) {  // layer 0, x-slice lane: 6-wide rows zero-padded
#pragma unroll
        for (int q = 0; q < 4; ++q) {
            const float ksc = (q == 2) ? LOG2E2 : LOG2E;
            const float* rp = Wih + ((q << 6) + j) * 6;
            w[q][0] = make_float4(rp[0] * ksc, rp[1] * ksc, rp[2] * ksc, rp[3] * ksc);
            w[q][1].x = rp[4] * ksc; w[q][1].y = rp[5] * ksc;
        }
    }
    // e == 3 on layer 0: all-zero slice (harmless)

    // per-gate bias * ksc / 4 (4-lane reduce sums 4 copies -> full bias)
    const float b0 = (bih[0 * 64 + j] + bhh[0 * 64 + j]) * (LOG2E * 0.25f);
    const float b1 = (bih[1 * 64 + j] + bhh[1 * 64 + j]) * (LOG2E * 0.25f);
    const float b2 = (bih[2 * 64 + j] + bhh[2 * 64 + j]) * (LOG2E2 * 0.25f);
    const float b3 = (bih[3 * 64 + j] + bhh[3 * 64 + j]) * (LOG2E * 0.25f);

    const float sg = (e == 2) ? 2.f : 1.f;   // lane e holds gate e; tanh=2s-1
    const float og = (e == 2) ? -1.f : 0.f;

    // zero hist; layer 0 also zeros xc (cols >=6 stay 0 forever)
    if (FIRST) { for (int i = tid; i < SMEMF; i += NT) smem[i] = 0.f; }
    else       { for (int i = HIST0 + tid; i < SMEMF; i += NT) smem[i] = 0.f; }
    __syncthreads();

    // ---- wait for producer's chunk 0, then stage it ----
    if (!FIRST) {
        if (tid == 0) {
            while (__hip_atomic_load(fin, __ATOMIC_ACQUIRE, __HIP_MEMORY_SCOPE_AGENT) < 1)
                __builtin_amdgcn_s_sleep(8);
        }
        __syncthreads();
    }

    const int srow = tid >> 4;           // 0..15
    const int scol = (tid & 15) << 2;    // float4 col
    const float* gp = nullptr;
    const float* xp = nullptr;
    if (!FIRST) {
        gp = seq + ((size_t)srow * BB + b) * HH + scol;
        float4 v = *(const float4*)gp;
        *(float4*)&smem[XC0 + srow * 64 + scol] = v;
        gp += (size_t)CH * BB * HH;      // -> chunk 1
    } else {
        xp = xg + (size_t)b * TT * 6 + tid * 4;
        if (tid < 24) {
            float4 v = *(const float4*)xp;
            float tmp[4] = {v.x, v.y, v.z, v.w};
#pragma unroll
            for (int m = 0; m < 4; ++m) {
                int idx = tid * 4 + m;
                smem[XC0 + (idx / 6) * 64 + (idx % 6)] = tmp[m];
            }
        }
        xp += 96;
    }
    float* sp = seq + ((size_t)srow * BB + b) * HH + scol;   // flush ptr
    float c = 0.f;
    __syncthreads();

    float4 pf4 = make_float4(0.f, 0.f, 0.f, 0.f);

    for (int ck = 0; ck < NCH; ++ck) {
        const int buf = ck & 1;
        // per-lane read bases: step ph reads vb + ph*64 (h: row ph-1; x: row ph)
        const float* vb  = kbh ? (smem + HIST0 - 64 + e * 32)
                               : (smem + XC0 + buf * 1024 + (e - 2) * 32);
        const float* vb0 = kbh ? (smem + HIST0 + 15 * 64 + e * 32) : vb;
        const bool pfv = (ck + 1 < NCH);

        // before prefetching chunk ck+1, ensure producer published it
        if (!FIRST && pfv) {
            if (tid == 0) {
                while (__hip_atomic_load(fin, __ATOMIC_ACQUIRE, __HIP_MEMORY_SCOPE_AGENT) < ck + 2)
                    __builtin_amdgcn_s_sleep(8);
            }
            __syncthreads();
        }

#pragma unroll
        for (int ph = 0; ph < CH; ++ph) {
            if (ph == 0 && pfv) {   // issue next-chunk global loads
                if (!FIRST) pf4 = *(const float4*)gp;
                else if (tid < 24) pf4 = *(const float4*)xp;
            }

            const float4* vp = (const float4*)((ph == 0) ? vb0 : (vb + ph * 64));
            const float4 vv0 = vp[0], vv1 = vp[1], vv2 = vp[2], vv3 = vp[3];
            const float4 vv4 = vp[4], vv5 = vp[5], vv6 = vp[6], vv7 = vp[7];

            // gate chains: 32 MAC over the thread's 32-float slice; bias/4
            // folded into pa's first fma; 4 parallel sub-chains for ILP
#define GATE(q, bq, aq) { \
            float pa = fmaf(w[q][0].x, vv0.x, bq); \
            pa = fmaf(w[q][0].y, vv0.y, pa); \
            pa = fmaf(w[q][0].z, vv0.z, pa); \
            pa = fmaf(w[q][0].w, vv0.w, pa); \
            float pb = w[q][1].x * vv1.x; \
            pb = fmaf(w[q][1].y, vv1.y, pb); \
            pb = fmaf(w[q][1].z, vv1.z, pb); \
            pb = fmaf(w[q][1].w, vv1.w, pb); \
            float pc = w[q][2].x * vv2.x; \
            pc = fmaf(w[q][2].y, vv2.y, pc); \
            pc = fmaf(w[q][2].z, vv2.z, pc); \
            pc = fmaf(w[q][2].w, vv2.w, pc); \
            float pd = w[q][3].x * vv3.x; \
            pd = fmaf(w[q][3].y, vv3.y, pd); \
            pd = fmaf(w[q][3].z, vv3.z, pd); \
            pd = fmaf(w[q][3].w, vv3.w, pd); \
            pa = fmaf(w[q][4].x, vv4.x, pa); \
            pa = fmaf(w[q][4].y, vv4.y, pa); \
            pa = fmaf(w[q][4].z, vv4.z, pa); \
            pa = fmaf(w[q][4].w, vv4.w, pa); \
            pb = fmaf(w[q][5].x, vv5.x, pb); \
            pb = fmaf(w[q][5].y, vv5.y, pb); \
            pb = fmaf(w[q][5].z, vv5.z, pb); \
            pb = fmaf(w[q][5].w, vv5.w, pb); \
            pc = fmaf(w[q][6].x, vv6.x, pc); \
            pc = fmaf(w[q][6].y, vv6.y, pc); \
            pc = fmaf(w[q][6].z, vv6.z, pc); \
            pc = fmaf(w[q][6].w, vv6.w, pc); \
            pd = fmaf(w[q][7].x, vv7.x, pd); \
            pd = fmaf(w[q][7].y, vv7.y, pd); \
            pd = fmaf(w[q][7].z, vv7.z, pd); \
            pd = fmaf(w[q][7].w, vv7.w, pd); \
            aq = (pa + pb) + (pc + pd); }
            float a0, a1, a2, a3;
            GATE(0, b0, a0) GATE(1, b1, a1) GATE(2, b2, a2) GATE(3, b3, a3)
#undef GATE

            // reduce-scatter over 4 lanes: stage1 xor1 (h-halves / x-halves),
            // stage2 xor2 (h+x) -> lane e holds gate e complete. No xor4.
            const float s0 = dpp_xor1(a0), s1 = dpp_xor1(a1);
            const float s2 = dpp_xor1(a2), s3 = dpp_xor1(a3);
            const float k0 = qb0 ? (a1 + s1) : (a0 + s0);
            const float k2 = qb0 ? (a3 + s3) : (a2 + s2);
            const float u0 = dpp_xor2(k0), u2 = dpp_xor2(k2);
            const float g = qb1 ? (k2 + u2) : (k0 + u0);

            // act: sigm via native exp2 (log2e pre-folded into w/b)
            const float act = fmaf(sg, frcp(1.f + exp2f(-g)), og);

            // gather acts (lane e^m holds gate e^m), replicated c/h update
            const float v1 = dpp_xor1(act);
            const float v2 = dpp_xor2(act);
            const float v3 = dpp_xor2(v1);
            const float px = act * v2, py = v1 * v3;
            const float P1 = qb0 ? py : px;   // sigm(i)*tanh(g)
            const float A  = qb0 ? act : v1;
            const float Bx = qb0 ? v2 : v3;
            const float fv = qb1 ? Bx : A;    // sigm(f)
            const float ov = qb1 ? A : Bx;    // sigm(o)

            c = fmaf(fv, c, P1);
            const float tc = fmaf(2.f, frcp(1.f + exp2f(c * -LOG2E2)), -1.f);  // tanh(c)
            const float hn = ov * tc;

            if (e == 0) smem[HIST0 + ph * 64 + j] = hn;   // hist[ph] = h(t)

            if (ph == 8 && pfv) {   // land next-chunk stage
                if (!FIRST) {
                    *(float4*)&smem[XC0 + (1 - buf) * 1024 + srow * 64 + scol] = pf4;
                } else if (tid < 24) {
                    float tmp[4] = {pf4.x, pf4.y, pf4.z, pf4.w};
#pragma unroll
                    for (int m = 0; m < 4; ++m) {
                        int idx = tid * 4 + m;
                        smem[XC0 + (1 - buf) * 1024 + (idx / 6) * 64 + (idx % 6)] = tmp[m];
                    }
                }
            }

            if (ph < CH - 1) lds_barrier();   // LDS-only sync
            else             __syncthreads(); // chunk boundary
        }

        // flush hist rows 0..15 -> seq rows ck*16..+15, then publish chunk
        if (!LAST) {
            float4 hv = *(const float4*)&smem[HIST0 + srow * 64 + scol];
            *(float4*)sp = hv;
            __syncthreads();   // drains stores + protects hist[0]
            if (tid == 0)
                __hip_atomic_store(fout, ck + 1, __ATOMIC_RELEASE, __HIP_MEMORY_SCOPE_AGENT);
        } else if (ck == NCH - 1) {
            if (srow == 15) {
                float4 hv = *(const float4*)&smem[HIST0 + 15 * 64 + scol];
                *(float4*)sp = hv;
            }
        }
        sp += (size_t)CH * BB * HH;
        if (!FIRST) gp += (size_t)CH * BB * HH;
        else        xp += 96;
    }
}

// out[b] = fc_b + sum_j relu(h[T-1][b][j]) * fc_w[j]
__global__ __launch_bounds__(256)
void fc_kernel(const float* __restrict__ seq, const float* __restrict__ fcw,
               const float* __restrict__ fcb, float* __restrict__ out)
{
    __shared__ float w[HH];
    const int tid = threadIdx.x;
    if (tid < HH) w[tid] = fcw[tid];
    __syncthreads();
    const float* h = &seq[((size_t)(TT - 1) * BB + tid) * HH];
    float s = fcb[0];
#pragma unroll
    for (int jj = 0; jj < HH; ++jj)
        s = fmaf(fmaxf(h[jj], 0.f), w[jj], s);
    out[tid] = s;
}

extern "C" void kernel_launch(void* const* d_in, const int* in_sizes, int n_in,
                              void* d_out, int out_size, void* d_ws, size_t ws_size,
                              hipStream_t stream) {
    const float* x    = (const float*)d_in[0];  // [B][T][6]
    const float* Wih0 = (const float*)d_in[1];  // [256][6]
    const float* WihR = (const float*)d_in[2];  // [3][256][64]
    const float* Whh  = (const float*)d_in[3];  // [4][256][64]
    const float* bih  = (const float*)d_in[4];  // [4][256]
    const float* bhh  = (const float*)d_in[5];  // [4][256]
    const float* fcw  = (const float*)d_in[6];  // [1][64]
    const float* fcb  = (const float*)d_in[7];  // [1]
    float* out = (float*)d_out;
    float* seq = (float*)d_ws;                  // [T][B][64] fp32 = 268 MB

    zero_flags_kernel<<<dim3(1), dim3(3 * BB), 0, stream>>>();
    lstm_pipe<<<dim3(4 * BB), dim3(NT), 0, stream>>>(x, Wih0, WihR, Whh, bih, bhh, seq);
    fc_kernel<<<dim3(1), dim3(256), 0, stream>>>(seq, fcw, fcb, out);
}